// Round 7
// baseline (2954.372 us; speedup 1.0000x reference)
//
#include <hip/hip_runtime.h>
#include <math.h>

#define NROWS 16384      // 32*512
#define DDIM  512
#define NE    4096
#define NZ    (NROWS * DDIM)
#define NGRP  128            // 32-code groups per row
#define MARGIN 4e-3f         // >= 6x worst-case bf16 approx error bound (1.1e-3)

typedef __attribute__((ext_vector_type(8))) short bf16x8;
typedef __attribute__((ext_vector_type(4))) float f32x4;

__device__ __forceinline__ float sqr_rn(float x) { return __fmul_rn(x, x); }
__device__ __forceinline__ ushort f2bf(float f) {   // RNE f32->bf16
    const unsigned u = __float_as_uint(f);
    return (ushort)((u + 0x7fffu + ((u >> 16) & 1u)) >> 16);
}

// ---------------- kernel 0a: numpy-exact pairwise partial sums of z*z ----------------
__global__ void k_znormB(const float* __restrict__ z, float* __restrict__ Bsum) {
    const int t = blockIdx.x * blockDim.x + threadIdx.x;   // 0 .. NROWS*4-1
    const int row = t >> 2, blk = t & 3;
    const float4* p = (const float4*)(z + (size_t)row * DDIM + blk * 128);
    float4 v0 = p[0], v1 = p[1];
    float r[8];
    r[0] = sqr_rn(v0.x); r[1] = sqr_rn(v0.y); r[2] = sqr_rn(v0.z); r[3] = sqr_rn(v0.w);
    r[4] = sqr_rn(v1.x); r[5] = sqr_rn(v1.y); r[6] = sqr_rn(v1.z); r[7] = sqr_rn(v1.w);
    #pragma unroll
    for (int i = 1; i < 16; ++i) {
        v0 = p[2 * i]; v1 = p[2 * i + 1];
        r[0] = __fadd_rn(r[0], sqr_rn(v0.x)); r[1] = __fadd_rn(r[1], sqr_rn(v0.y));
        r[2] = __fadd_rn(r[2], sqr_rn(v0.z)); r[3] = __fadd_rn(r[3], sqr_rn(v0.w));
        r[4] = __fadd_rn(r[4], sqr_rn(v1.x)); r[5] = __fadd_rn(r[5], sqr_rn(v1.y));
        r[6] = __fadd_rn(r[6], sqr_rn(v1.z)); r[7] = __fadd_rn(r[7], sqr_rn(v1.w));
    }
    Bsum[t] = __fadd_rn(__fadd_rn(__fadd_rn(r[0], r[1]), __fadd_rn(r[2], r[3])),
                        __fadd_rn(__fadd_rn(r[4], r[5]), __fadd_rn(r[6], r[7])));
}

__global__ void k_znfin(const float* __restrict__ Bsum, float* __restrict__ znorm) {
    const int row = blockIdx.x * blockDim.x + threadIdx.x;
    if (row >= NROWS) return;
    const float4 b = *(const float4*)(Bsum + (size_t)row * 4);
    znorm[row] = __fadd_rn(__fadd_rn(b.x, b.y), __fadd_rn(b.z, b.w));
}

// ---------------- kernel 1: codebook squared norms (sub-ulp of zz; order-free) ----------
__global__ void k_bnorm(const float* __restrict__ emb, float* __restrict__ bnorm) {
    const int lane = threadIdx.x & 63;
    const int wid  = (blockIdx.x * blockDim.x + threadIdx.x) >> 6;
    const int nw   = (gridDim.x * blockDim.x) >> 6;
    for (int c = wid; c < NE; c += nw) {
        const float4* p = (const float4*)(emb + (size_t)c * DDIM);
        float4 v0 = p[lane * 2];
        float4 v1 = p[lane * 2 + 1];
        float s = v0.x*v0.x + v0.y*v0.y + v0.z*v0.z + v0.w*v0.w
                + v1.x*v1.x + v1.y*v1.y + v1.z*v1.z + v1.w*v1.w;
        #pragma unroll
        for (int m = 32; m; m >>= 1) s += __shfl_xor(s, m);
        if (lane == 0) bnorm[c] = s;
    }
}

// ---------------- kernel 2: f32 -> bf16 (RNE), vectorized ----------------
__global__ void k_cvt(const float* __restrict__ x, ushort* __restrict__ y, int n4) {
    const int i = blockIdx.x * blockDim.x + threadIdx.x;
    if (i >= n4) return;
    const float4 v = ((const float4*)x)[i];
    ushort4 o; o.x = f2bf(v.x); o.y = f2bf(v.y); o.z = f2bf(v.z); o.w = f2bf(v.w);
    ((ushort4*)y)[i] = o;
}

// ---------------- kernel 3: bf16 MFMA GEMM + fused per-32-col-group row mins -----------
// grid (128, 32), block 256 = 4 waves (2x2 of 64x64). Tile 128x128, BK=32.
// A/B frag: matrix-row/col = lane&15; k = (lane>>4)*4 + {0..3} and 16+(lane>>4)*4 + {0..3}.
// C/D: col = lane&15, row = (lane>>4)*4 + reg.
__global__ __launch_bounds__(256) void k_mfma(const ushort* __restrict__ zh,
                                              const ushort* __restrict__ eh,
                                              const float* __restrict__ bnorm,
                                              float* __restrict__ gout) {
    __shared__ ushort Ab[128 * 40];   // 40-ushort row stride (80B): conflict-tame
    __shared__ ushort Bb[128 * 40];
    const int tid = threadIdx.x;
    const int lane = tid & 63;
    const int w = tid >> 6;
    const int wrow = (w >> 1) * 64, wcol = (w & 1) * 64;
    const int rbase = blockIdx.x * 128, cbase = blockIdx.y * 128;
    const int srow = tid >> 1, shalf = tid & 1;       // staging: (row, 16-elem half)
    const int r16 = lane & 15, g4 = (lane >> 4) * 4;  // frag row/col, k-subgroup

    f32x4 acc[4][4];
    #pragma unroll
    for (int i = 0; i < 4; ++i)
        #pragma unroll
        for (int j = 0; j < 4; ++j) acc[i][j] = (f32x4){0.f, 0.f, 0.f, 0.f};

    for (int kb = 0; kb < DDIM; kb += 32) {
        // issue global loads early (latency overlaps previous MFMA phase)
        const ushort* ga = zh + (size_t)(rbase + srow) * DDIM + kb + shalf * 16;
        const ushort* gb = eh + (size_t)(cbase + srow) * DDIM + kb + shalf * 16;
        const uint4 a0 = *(const uint4*)ga;
        const uint4 a1 = *(const uint4*)(ga + 8);
        const uint4 b0 = *(const uint4*)gb;
        const uint4 b1 = *(const uint4*)(gb + 8);
        __syncthreads();   // prior iteration's frag reads complete
        *(uint4*)&Ab[srow * 40 + shalf * 16]     = a0;
        *(uint4*)&Ab[srow * 40 + shalf * 16 + 8] = a1;
        *(uint4*)&Bb[srow * 40 + shalf * 16]     = b0;
        *(uint4*)&Bb[srow * 40 + shalf * 16 + 8] = b1;
        __syncthreads();   // tile visible
        bf16x8 af[4], bf[4];
        #pragma unroll
        for (int f = 0; f < 4; ++f) {
            const ushort* pa = &Ab[(wrow + f * 16 + r16) * 40 + g4];
            uint4 ta;
            *(uint2*)&ta.x = *(const uint2*)pa;            // k = g4..g4+3
            *(uint2*)&ta.z = *(const uint2*)(pa + 16);     // k = 16+g4..
            af[f] = *(bf16x8*)&ta;
            const ushort* pb = &Bb[(wcol + f * 16 + r16) * 40 + g4];
            uint4 tb;
            *(uint2*)&tb.x = *(const uint2*)pb;
            *(uint2*)&tb.z = *(const uint2*)(pb + 16);
            bf[f] = *(bf16x8*)&tb;
        }
        #pragma unroll
        for (int fi = 0; fi < 4; ++fi)
            #pragma unroll
            for (int fj = 0; fj < 4; ++fj)
                acc[fi][fj] = __builtin_amdgcn_mfma_f32_16x16x32_bf16(
                    af[fi], bf[fj], acc[fi][fj], 0, 0, 0);
    }

    // epilogue: s' = ee - 2*dot'; per-row min over each 32-col group; write gout[row][G]
    #pragma unroll
    for (int fp = 0; fp < 2; ++fp) {
        const float bn0 = bnorm[cbase + wcol + fp * 32 + r16];
        const float bn1 = bnorm[cbase + wcol + fp * 32 + 16 + r16];
        const int G = blockIdx.y * 4 + (wcol >> 5) + fp;
        #pragma unroll
        for (int fi = 0; fi < 4; ++fi) {
            float mn[4];
            #pragma unroll
            for (int r = 0; r < 4; ++r) {
                const float s0 = fmaf(-2.f, acc[fi][2 * fp][r], bn0);
                const float s1 = fmaf(-2.f, acc[fi][2 * fp + 1][r], bn1);
                mn[r] = fminf(s0, s1);
            }
            #pragma unroll
            for (int m = 1; m < 16; m <<= 1)
                #pragma unroll
                for (int r = 0; r < 4; ++r) mn[r] = fminf(mn[r], __shfl_xor(mn[r], m));
            if (r16 == 0) {
                const int rowb = rbase + wrow + fi * 16 + (lane >> 4) * 4;
                #pragma unroll
                for (int r = 0; r < 4; ++r)
                    gout[(size_t)(rowb + r) * NGRP + G] = mn[r];
            }
        }
    }
}

// ---------------- kernel 4: exact resolve of candidate groups ----------------
// one wave per row. Rescan every group within MARGIN of the approx min with the
// numpy-exact chain: sequential ascending-k FMA dot, d = fl(fl(zz+ee)-fl(2dot)),
// (bucket, index) lexicographic min == reference argmin semantics.
__global__ void k_resolve(const float* __restrict__ gout, const float* __restrict__ z,
                          const float* __restrict__ emb, const float* __restrict__ znorm,
                          const float* __restrict__ bnorm, int* __restrict__ idxbuf) {
    const int lane = threadIdx.x & 63;
    const int row = blockIdx.x * 4 + (threadIdx.x >> 6);
    const float* gp = gout + (size_t)row * NGRP;
    const float v0 = gp[lane];
    const float v1 = gp[64 + lane];
    float gm = fminf(v0, v1);
    #pragma unroll
    for (int m = 32; m; m >>= 1) gm = fminf(gm, __shfl_xor(gm, m));
    const float thr = gm + MARGIN;
    unsigned long long m0 = __ballot(v0 <= thr);
    unsigned long long m1 = __ballot(v1 <= thr);

    const float zn = znorm[row];
    const float* zp = z + (size_t)row * DDIM;
    unsigned long long best = ~0ULL;
    #pragma unroll
    for (int half = 0; half < 2; ++half) {
        unsigned long long mm = half ? m1 : m0;
        while (mm) {
            const int g = __builtin_ctzll(mm); mm &= mm - 1;
            const int c = (half * 64 + g) * 32 + (lane & 31);   // lanes>=32 duplicate: same keys
            const float* ep = emb + (size_t)c * DDIM;
            float acc = 0.f;
            #pragma unroll 8
            for (int k = 0; k < DDIM; ++k) acc = fmaf(zp[k], ep[k], acc);
            const float s = __fsub_rn(__fadd_rn(zn, bnorm[c]), __fmul_rn(2.f, acc));
            const unsigned long long key =
                ((unsigned long long)__float_as_uint(s) << 32) | (unsigned)c;
            if (key < best) best = key;
        }
    }
    #pragma unroll
    for (int m = 32; m; m >>= 1) {
        const unsigned long long ov = __shfl_xor(best, m);
        if (ov < best) best = ov;
    }
    if (lane == 0) idxbuf[row] = (int)(best & 0xffffffffu);
}

// ---------------- kernel 5: gather + STE + counts + loss partials ----------------
__global__ void k_gather(const float* __restrict__ z, const float* __restrict__ emb,
                         const int* __restrict__ idxbuf, float* __restrict__ out,
                         unsigned* __restrict__ counts, float* __restrict__ d2buf) {
    const int lane = threadIdx.x & 63;
    const int row = blockIdx.x * 4 + (threadIdx.x >> 6);
    const int id = idxbuf[row];

    const float* ep = emb + (size_t)id * DDIM;
    const float* zp = z + (size_t)row * DDIM;
    float* op = out + 1 + (size_t)row * DDIM;
    float d2 = 0.f;
    #pragma unroll
    for (int m = 0; m < 8; ++m) {
        const int k = m * 64 + lane;
        const float e = ep[k];
        const float zv = zp[k];
        const float t = e - zv;          // two-step rounding matches reference STE
        op[k] = zv + t;
        d2 = fmaf(t, t, d2);
    }
    #pragma unroll
    for (int m = 32; m; m >>= 1) d2 += __shfl_xor(d2, m);
    if (lane == 0) {
        atomicAdd(&counts[id], 1u);
        d2buf[row] = d2;
        out[1 + (size_t)NZ + row] = (float)id;
    }
}

// ---------------- kernel 6: finalize loss + perplexity ----------------
__global__ void k_final(const float* __restrict__ d2buf, const unsigned* __restrict__ counts,
                        float* __restrict__ out) {
    __shared__ double sh[256];
    __shared__ float  shf[256];
    const int tid = threadIdx.x;
    double ent = 0.0;
    for (int i = tid; i < NE; i += 256) {
        const double p = (double)counts[i] / (double)NROWS;
        ent += p * log(p + 1e-10);
    }
    float sse = 0.f;
    for (int i = tid; i < NROWS; i += 256) sse += d2buf[i];
    sh[tid] = ent; shf[tid] = sse;
    __syncthreads();
    for (int s = 128; s; s >>= 1) {
        if (tid < s) { sh[tid] += sh[tid + s]; shf[tid] += shf[tid + s]; }
        __syncthreads();
    }
    if (tid == 0) {
        out[0] = 1.25f * (shf[0] / (float)NZ);
        out[1 + (size_t)NZ + NROWS] = (float)exp(-sh[0]);
    }
}

extern "C" void kernel_launch(void* const* d_in, const int* in_sizes, int n_in,
                              void* d_out, int out_size, void* d_ws, size_t ws_size,
                              hipStream_t stream) {
    const float* z   = (const float*)d_in[0];
    const float* emb = (const float*)d_in[1];
    float* out = (float*)d_out;
    char* ws = (char*)d_ws;

    // big intermediates live inside out[1..NZ] (k_gather overwrites them afterwards);
    // all offsets 16B-aligned.
    ushort* zh   = (ushort*)(out + 4);                       // 16 MB  (4,194,304 floats)
    ushort* eh   = (ushort*)(out + 4 + 4194304);             //  4 MB  (1,048,576 floats)
    float*  gout = out + 4 + 4194304 + 1048576;              //  8 MB  (ends @7,340,036 < NZ)

    size_t off = 0;
    float*    bnorm  = (float*)(ws + off); off += (size_t)NE * 4;          // 16KB
    unsigned* counts = (unsigned*)(ws + off); off += (size_t)NE * 4;       // 16KB
    float*    d2buf  = (float*)(ws + off); off += (size_t)NROWS * 4;       // 64KB
    float*    Bsum   = (float*)(ws + off); off += (size_t)NROWS * 4 * 4;   // 256KB
    float*    znorm  = (float*)(ws + off); off += (size_t)NROWS * 4;       // 64KB
    int*      idxbuf = (int*)(ws + off); off += (size_t)NROWS * 4;         // 64KB

    hipMemsetAsync(counts, 0, NE * sizeof(unsigned), stream);
    k_znormB<<<(NROWS * 4) / 256, 256, 0, stream>>>(z, Bsum);
    k_znfin<<<NROWS / 256, 256, 0, stream>>>(Bsum, znorm);
    k_bnorm<<<64, 256, 0, stream>>>(emb, bnorm);
    k_cvt<<<(NZ / 4) / 256, 256, 0, stream>>>(z, zh, NZ / 4);
    k_cvt<<<((NE * DDIM) / 4) / 256, 256, 0, stream>>>(emb, eh, (NE * DDIM) / 4);
    k_mfma<<<dim3(NROWS / 128, NE / 128), 256, 0, stream>>>(zh, eh, bnorm, gout);
    k_resolve<<<NROWS / 4, 256, 0, stream>>>(gout, z, emb, znorm, bnorm, idxbuf);
    k_gather<<<NROWS / 4, 256, 0, stream>>>(z, emb, idxbuf, out, counts, d2buf);
    k_final<<<1, 256, 0, stream>>>(d2buf, counts, out);
}

// Round 8
// 471.757 us; speedup vs baseline: 6.2625x; 6.2625x over previous
//
#include <hip/hip_runtime.h>
#include <math.h>

#define NROWS 16384      // 32*512
#define DDIM  512
#define NE    4096
#define NZ    (NROWS * DDIM)
#define MAXC  32             // per-row candidate cap (expected ~2.1, worst-case margin math << 32)
#define MARGIN 2e-3f         // >= 1.57x worst-case bound 2E + bucket = 1.27e-3

typedef __attribute__((ext_vector_type(8))) short bf16x8;
typedef __attribute__((ext_vector_type(4))) float f32x4;

__device__ __forceinline__ float sqr_rn(float x) { return __fmul_rn(x, x); }
__device__ __forceinline__ ushort f2bf(float f) {   // RNE f32->bf16
    const unsigned u = __float_as_uint(f);
    return (ushort)((u + 0x7fffu + ((u >> 16) & 1u)) >> 16);
}

// ---------------- kernel 0a: numpy-exact pairwise partial sums of z*z ----------------
__global__ void k_znormB(const float* __restrict__ z, float* __restrict__ Bsum) {
    const int t = blockIdx.x * blockDim.x + threadIdx.x;   // 0 .. NROWS*4-1
    const int row = t >> 2, blk = t & 3;
    const float4* p = (const float4*)(z + (size_t)row * DDIM + blk * 128);
    float4 v0 = p[0], v1 = p[1];
    float r[8];
    r[0] = sqr_rn(v0.x); r[1] = sqr_rn(v0.y); r[2] = sqr_rn(v0.z); r[3] = sqr_rn(v0.w);
    r[4] = sqr_rn(v1.x); r[5] = sqr_rn(v1.y); r[6] = sqr_rn(v1.z); r[7] = sqr_rn(v1.w);
    #pragma unroll
    for (int i = 1; i < 16; ++i) {
        v0 = p[2 * i]; v1 = p[2 * i + 1];
        r[0] = __fadd_rn(r[0], sqr_rn(v0.x)); r[1] = __fadd_rn(r[1], sqr_rn(v0.y));
        r[2] = __fadd_rn(r[2], sqr_rn(v0.z)); r[3] = __fadd_rn(r[3], sqr_rn(v0.w));
        r[4] = __fadd_rn(r[4], sqr_rn(v1.x)); r[5] = __fadd_rn(r[5], sqr_rn(v1.y));
        r[6] = __fadd_rn(r[6], sqr_rn(v1.z)); r[7] = __fadd_rn(r[7], sqr_rn(v1.w));
    }
    Bsum[t] = __fadd_rn(__fadd_rn(__fadd_rn(r[0], r[1]), __fadd_rn(r[2], r[3])),
                        __fadd_rn(__fadd_rn(r[4], r[5]), __fadd_rn(r[6], r[7])));
}

__global__ void k_znfin(const float* __restrict__ Bsum, float* __restrict__ znorm) {
    const int row = blockIdx.x * blockDim.x + threadIdx.x;
    if (row >= NROWS) return;
    const float4 b = *(const float4*)(Bsum + (size_t)row * 4);
    znorm[row] = __fadd_rn(__fadd_rn(b.x, b.y), __fadd_rn(b.z, b.w));
}

// ---------------- kernel 1: codebook squared norms (sub-ulp of zz; order-free) ----------
__global__ void k_bnorm(const float* __restrict__ emb, float* __restrict__ bnorm) {
    const int lane = threadIdx.x & 63;
    const int wid  = (blockIdx.x * blockDim.x + threadIdx.x) >> 6;
    const int nw   = (gridDim.x * blockDim.x) >> 6;
    for (int c = wid; c < NE; c += nw) {
        const float4* p = (const float4*)(emb + (size_t)c * DDIM);
        float4 v0 = p[lane * 2];
        float4 v1 = p[lane * 2 + 1];
        float s = v0.x*v0.x + v0.y*v0.y + v0.z*v0.z + v0.w*v0.w
                + v1.x*v1.x + v1.y*v1.y + v1.z*v1.z + v1.w*v1.w;
        #pragma unroll
        for (int m = 32; m; m >>= 1) s += __shfl_xor(s, m);
        if (lane == 0) bnorm[c] = s;
    }
}

// ---------------- kernel 2: f32 -> bf16 (RNE), vectorized ----------------
__global__ void k_cvt(const float* __restrict__ x, ushort* __restrict__ y, int n4) {
    const int i = blockIdx.x * blockDim.x + threadIdx.x;
    if (i >= n4) return;
    const float4 v = ((const float4*)x)[i];
    ushort4 o; o.x = f2bf(v.x); o.y = f2bf(v.y); o.z = f2bf(v.z); o.w = f2bf(v.w);
    ((ushort4*)y)[i] = o;
}

// ---------------- kernel 3: bf16 MFMA GEMM, templated epilogue ----------------
// grid (128, 32), block 256 = 4 waves (2x2 of 64x64). Tile 128x128, BK=32.
// PASS 1: per-row global min of s' = ee - 2*dot'  (atomicMin on +1.0f-biased f32 bits)
// PASS 2: append codes with s' <= rowmin + MARGIN to per-row candidate list
template <int PASS>
__global__ __launch_bounds__(256) void k_mfma(const ushort* __restrict__ zh,
                                              const ushort* __restrict__ eh,
                                              const float* __restrict__ bnorm,
                                              unsigned* __restrict__ rowmin,
                                              unsigned* __restrict__ ccnt,
                                              unsigned* __restrict__ cand) {
    __shared__ ushort Ab[128 * 40];   // 40-ushort row stride (80B)
    __shared__ ushort Bb[128 * 40];
    const int tid = threadIdx.x;
    const int lane = tid & 63;
    const int w = tid >> 6;
    const int wrow = (w >> 1) * 64, wcol = (w & 1) * 64;
    const int rbase = blockIdx.x * 128, cbase = blockIdx.y * 128;
    const int srow = tid >> 1, shalf = tid & 1;       // staging: (row, 16-elem half)
    const int r16 = lane & 15, g4 = (lane >> 4) * 4;  // frag row/col, k-subgroup

    f32x4 acc[4][4];
    #pragma unroll
    for (int i = 0; i < 4; ++i)
        #pragma unroll
        for (int j = 0; j < 4; ++j) acc[i][j] = (f32x4){0.f, 0.f, 0.f, 0.f};

    for (int kb = 0; kb < DDIM; kb += 32) {
        const ushort* ga = zh + (size_t)(rbase + srow) * DDIM + kb + shalf * 16;
        const ushort* gb = eh + (size_t)(cbase + srow) * DDIM + kb + shalf * 16;
        const uint4 a0 = *(const uint4*)ga;
        const uint4 a1 = *(const uint4*)(ga + 8);
        const uint4 b0 = *(const uint4*)gb;
        const uint4 b1 = *(const uint4*)(gb + 8);
        __syncthreads();   // prior iteration's frag reads complete
        *(uint4*)&Ab[srow * 40 + shalf * 16]     = a0;
        *(uint4*)&Ab[srow * 40 + shalf * 16 + 8] = a1;
        *(uint4*)&Bb[srow * 40 + shalf * 16]     = b0;
        *(uint4*)&Bb[srow * 40 + shalf * 16 + 8] = b1;
        __syncthreads();   // tile visible
        bf16x8 af[4], bf[4];
        #pragma unroll
        for (int f = 0; f < 4; ++f) {
            const ushort* pa = &Ab[(wrow + f * 16 + r16) * 40 + g4];
            uint4 ta;
            *(uint2*)&ta.x = *(const uint2*)pa;            // k = g4..g4+3
            *(uint2*)&ta.z = *(const uint2*)(pa + 16);     // k = 16+g4..
            af[f] = *(bf16x8*)&ta;
            const ushort* pb = &Bb[(wcol + f * 16 + r16) * 40 + g4];
            uint4 tb;
            *(uint2*)&tb.x = *(const uint2*)pb;
            *(uint2*)&tb.z = *(const uint2*)(pb + 16);
            bf[f] = *(bf16x8*)&tb;
        }
        #pragma unroll
        for (int fi = 0; fi < 4; ++fi)
            #pragma unroll
            for (int fj = 0; fj < 4; ++fj)
                acc[fi][fj] = __builtin_amdgcn_mfma_f32_16x16x32_bf16(
                    af[fi], bf[fj], acc[fi][fj], 0, 0, 0);
    }

    // C/D layout: value (fi,fj,r) -> row = wrow+fi*16+g4+r, col = wcol+fj*16+r16
    float bn[4];
    #pragma unroll
    for (int fj = 0; fj < 4; ++fj) bn[fj] = bnorm[cbase + wcol + fj * 16 + r16];

    if (PASS == 1) {
        #pragma unroll
        for (int fi = 0; fi < 4; ++fi) {
            #pragma unroll
            for (int r = 0; r < 4; ++r) {
                float m = INFINITY;
                #pragma unroll
                for (int fj = 0; fj < 4; ++fj)
                    m = fminf(m, fmaf(-2.f, acc[fi][fj][r], bn[fj]));
                #pragma unroll
                for (int x = 1; x < 16; x <<= 1) m = fminf(m, __shfl_xor(m, x));
                if (r16 == 0)
                    atomicMin(&rowmin[rbase + wrow + fi * 16 + g4 + r],
                              __float_as_uint(m + 1.0f));   // s' in ±0.04 -> biased positive
            }
        }
    } else {
        #pragma unroll
        for (int fi = 0; fi < 4; ++fi) {
            #pragma unroll
            for (int r = 0; r < 4; ++r) {
                const int row = rbase + wrow + fi * 16 + g4 + r;
                const float thr = __uint_as_float(rowmin[row]) - 1.0f + MARGIN;
                #pragma unroll
                for (int fj = 0; fj < 4; ++fj) {
                    const float s = fmaf(-2.f, acc[fi][fj][r], bn[fj]);
                    if (s <= thr) {
                        const unsigned slot = atomicAdd(&ccnt[row], 1u);
                        if (slot < MAXC)
                            cand[(size_t)row * MAXC + slot] =
                                (unsigned)(cbase + wcol + fj * 16 + r16);
                    }
                }
            }
        }
    }
}

// ---------------- kernel 4: exact per-candidate resolve ----------------
// one wave per row; lane l owns candidate l. numpy-exact chain: sequential ascending-k
// FMA dot, d = fl(fl(zz+ee)-fl(2dot)) (positive ~512), (bucket,code) u64 min.
__global__ void k_exact(const unsigned* __restrict__ ccnt, const unsigned* __restrict__ cand,
                        const float* __restrict__ z, const float* __restrict__ emb,
                        const float* __restrict__ znorm, const float* __restrict__ bnorm,
                        int* __restrict__ idxbuf) {
    const int lane = threadIdx.x & 63;
    const int row = blockIdx.x * 4 + (threadIdx.x >> 6);
    const int cnt = min((int)ccnt[row], MAXC);
    if (cnt == 1) {          // unique candidate == exact winner
        if (lane == 0) idxbuf[row] = (int)cand[(size_t)row * MAXC];
        return;
    }
    unsigned long long best = ~0ULL;
    if (lane < cnt) {
        const int c = (int)cand[(size_t)row * MAXC + lane];
        const float4* zp4 = (const float4*)(z + (size_t)row * DDIM);   // broadcast across lanes
        const float4* ep4 = (const float4*)(emb + (size_t)c * DDIM);
        float acc = 0.f;
        #pragma unroll 8
        for (int q = 0; q < DDIM / 4; ++q) {
            const float4 zv = zp4[q];
            const float4 ev = ep4[q];
            acc = fmaf(zv.x, ev.x, acc);
            acc = fmaf(zv.y, ev.y, acc);
            acc = fmaf(zv.z, ev.z, acc);
            acc = fmaf(zv.w, ev.w, acc);
        }
        const float s = __fsub_rn(__fadd_rn(znorm[row], bnorm[c]), __fmul_rn(2.f, acc));
        best = ((unsigned long long)__float_as_uint(s) << 32) | (unsigned)c;
    }
    #pragma unroll
    for (int m = 32; m; m >>= 1) {
        const unsigned long long ov = __shfl_xor(best, m);
        if (ov < best) best = ov;
    }
    if (lane == 0) idxbuf[row] = (int)(best & 0xffffffffu);
}

// ---------------- kernel 5: gather + STE + counts + loss partials ----------------
__global__ void k_gather(const float* __restrict__ z, const float* __restrict__ emb,
                         const int* __restrict__ idxbuf, float* __restrict__ out,
                         unsigned* __restrict__ counts, float* __restrict__ d2buf) {
    const int lane = threadIdx.x & 63;
    const int row = blockIdx.x * 4 + (threadIdx.x >> 6);
    const int id = idxbuf[row];

    const float* ep = emb + (size_t)id * DDIM;
    const float* zp = z + (size_t)row * DDIM;
    float* op = out + 1 + (size_t)row * DDIM;
    float d2 = 0.f;
    #pragma unroll
    for (int m = 0; m < 8; ++m) {
        const int k = m * 64 + lane;
        const float e = ep[k];
        const float zv = zp[k];
        const float t = e - zv;          // two-step rounding matches reference STE
        op[k] = zv + t;
        d2 = fmaf(t, t, d2);
    }
    #pragma unroll
    for (int m = 32; m; m >>= 1) d2 += __shfl_xor(d2, m);
    if (lane == 0) {
        atomicAdd(&counts[id], 1u);
        d2buf[row] = d2;
        out[1 + (size_t)NZ + row] = (float)id;
    }
}

// ---------------- kernel 6: finalize loss + perplexity ----------------
__global__ void k_final(const float* __restrict__ d2buf, const unsigned* __restrict__ counts,
                        float* __restrict__ out) {
    __shared__ double sh[256];
    __shared__ float  shf[256];
    const int tid = threadIdx.x;
    double ent = 0.0;
    for (int i = tid; i < NE; i += 256) {
        const double p = (double)counts[i] / (double)NROWS;
        ent += p * log(p + 1e-10);
    }
    float sse = 0.f;
    for (int i = tid; i < NROWS; i += 256) sse += d2buf[i];
    sh[tid] = ent; shf[tid] = sse;
    __syncthreads();
    for (int s = 128; s; s >>= 1) {
        if (tid < s) { sh[tid] += sh[tid + s]; shf[tid] += shf[tid + s]; }
        __syncthreads();
    }
    if (tid == 0) {
        out[0] = 1.25f * (shf[0] / (float)NZ);
        out[1 + (size_t)NZ + NROWS] = (float)exp(-sh[0]);
    }
}

extern "C" void kernel_launch(void* const* d_in, const int* in_sizes, int n_in,
                              void* d_out, int out_size, void* d_ws, size_t ws_size,
                              hipStream_t stream) {
    const float* z   = (const float*)d_in[0];
    const float* emb = (const float*)d_in[1];
    float* out = (float*)d_out;
    char* ws = (char*)d_ws;

    // big intermediates live inside out[1..NZ] (k_gather overwrites them afterwards)
    ushort*   zh   = (ushort*)(out + 4);                       // 4,194,304 float-slots
    ushort*   eh   = (ushort*)(out + 4 + 4194304);             // 1,048,576 float-slots
    unsigned* cand = (unsigned*)(out + 4 + 4194304 + 1048576); //   524,288 float-slots

    size_t off = 0;
    float*    bnorm  = (float*)(ws + off); off += (size_t)NE * 4;          // 16KB
    unsigned* counts = (unsigned*)(ws + off); off += (size_t)NE * 4;       // 16KB
    float*    d2buf  = (float*)(ws + off); off += (size_t)NROWS * 4;       // 64KB
    float*    Bsum   = (float*)(ws + off); off += (size_t)NROWS * 4 * 4;   // 256KB
    float*    znorm  = (float*)(ws + off); off += (size_t)NROWS * 4;       // 64KB
    int*      idxbuf = (int*)(ws + off); off += (size_t)NROWS * 4;         // 64KB
    unsigned* rowmin = (unsigned*)(ws + off); off += (size_t)NROWS * 4;    // 64KB
    unsigned* ccnt   = (unsigned*)(ws + off); off += (size_t)NROWS * 4;    // 64KB

    hipMemsetAsync(counts, 0, NE * sizeof(unsigned), stream);
    hipMemsetAsync(ccnt, 0, NROWS * sizeof(unsigned), stream);
    hipMemsetAsync(rowmin, 0xFF, NROWS * sizeof(unsigned), stream);
    k_znormB<<<(NROWS * 4) / 256, 256, 0, stream>>>(z, Bsum);
    k_znfin<<<NROWS / 256, 256, 0, stream>>>(Bsum, znorm);
    k_bnorm<<<64, 256, 0, stream>>>(emb, bnorm);
    k_cvt<<<(NZ / 4) / 256, 256, 0, stream>>>(z, zh, NZ / 4);
    k_cvt<<<((NE * DDIM) / 4) / 256, 256, 0, stream>>>(emb, eh, (NE * DDIM) / 4);
    k_mfma<1><<<dim3(NROWS / 128, NE / 128), 256, 0, stream>>>(zh, eh, bnorm, rowmin, ccnt, cand);
    k_mfma<2><<<dim3(NROWS / 128, NE / 128), 256, 0, stream>>>(zh, eh, bnorm, rowmin, ccnt, cand);
    k_exact<<<NROWS / 4, 256, 0, stream>>>(ccnt, cand, z, emb, znorm, bnorm, idxbuf);
    k_gather<<<NROWS / 4, 256, 0, stream>>>(z, emb, idxbuf, out, counts, d2buf);
    k_final<<<1, 256, 0, stream>>>(d2buf, counts, out);
}

// Round 9
// 339.616 us; speedup vs baseline: 8.6992x; 1.3891x over previous
//
#include <hip/hip_runtime.h>
#include <math.h>

#define NROWS 16384      // 32*512
#define DDIM  512
#define NE    4096
#define NZ    (NROWS * DDIM)
#define MAXC  32             // per-row candidate cap (expected ~2.1)
#define MARGIN 2e-3f         // >= bound 2E + bucket + 2*bf16store = 1.39e-3

typedef __attribute__((ext_vector_type(8))) short bf16x8;
typedef __attribute__((ext_vector_type(4))) float f32x4;

__device__ __forceinline__ float sqr_rn(float x) { return __fmul_rn(x, x); }
__device__ __forceinline__ ushort f2bf(float f) {   // RNE f32->bf16
    const unsigned u = __float_as_uint(f);
    return (ushort)((u + 0x7fffu + ((u >> 16) & 1u)) >> 16);
}
__device__ __forceinline__ unsigned pack2(float a, float b) {
    return (unsigned)f2bf(a) | ((unsigned)f2bf(b) << 16);
}

// ---------------- kernel P1: numpy-exact znorm + z->bf16 + zero ccnt/rowmin ------------
// thread t: row t>>2, 128-elem block t&3. numpy pairwise: 8-acc unrolled block sums,
// then ((B0+B1)+(B2+B3)) via in-wave quad shuffle (4 | 64, never crosses a wave).
__global__ void k_prepZ(const float* __restrict__ z, ushort* __restrict__ zh,
                        float* __restrict__ znorm, unsigned* __restrict__ ccnt,
                        unsigned* __restrict__ rowmin) {
    const int t = blockIdx.x * blockDim.x + threadIdx.x;   // 0 .. 65535
    const int row = t >> 2, blk = t & 3;
    const float4* p = (const float4*)(z + (size_t)row * DDIM + blk * 128);
    ushort* zo = zh + (size_t)row * DDIM + blk * 128;
    float4 v0 = p[0], v1 = p[1];
    {
        uint4 w; w.x = pack2(v0.x, v0.y); w.y = pack2(v0.z, v0.w);
        w.z = pack2(v1.x, v1.y); w.w = pack2(v1.z, v1.w);
        *(uint4*)zo = w;
    }
    float r[8];
    r[0] = sqr_rn(v0.x); r[1] = sqr_rn(v0.y); r[2] = sqr_rn(v0.z); r[3] = sqr_rn(v0.w);
    r[4] = sqr_rn(v1.x); r[5] = sqr_rn(v1.y); r[6] = sqr_rn(v1.z); r[7] = sqr_rn(v1.w);
    #pragma unroll
    for (int i = 1; i < 16; ++i) {
        v0 = p[2 * i]; v1 = p[2 * i + 1];
        uint4 w; w.x = pack2(v0.x, v0.y); w.y = pack2(v0.z, v0.w);
        w.z = pack2(v1.x, v1.y); w.w = pack2(v1.z, v1.w);
        *(uint4*)(zo + i * 8) = w;
        r[0] = __fadd_rn(r[0], sqr_rn(v0.x)); r[1] = __fadd_rn(r[1], sqr_rn(v0.y));
        r[2] = __fadd_rn(r[2], sqr_rn(v0.z)); r[3] = __fadd_rn(r[3], sqr_rn(v0.w));
        r[4] = __fadd_rn(r[4], sqr_rn(v1.x)); r[5] = __fadd_rn(r[5], sqr_rn(v1.y));
        r[6] = __fadd_rn(r[6], sqr_rn(v1.z)); r[7] = __fadd_rn(r[7], sqr_rn(v1.w));
    }
    const float B = __fadd_rn(__fadd_rn(__fadd_rn(r[0], r[1]), __fadd_rn(r[2], r[3])),
                              __fadd_rn(__fadd_rn(r[4], r[5]), __fadd_rn(r[6], r[7])));
    const float s01 = __fadd_rn(B, __shfl_xor(B, 1));     // (B0+B1) / (B2+B3), comm-safe
    const float zn  = __fadd_rn(s01, __shfl_xor(s01, 2)); // ((B0+B1)+(B2+B3))
    if (blk == 0) znorm[row] = zn;
    if (t < NROWS) { ccnt[t] = 0u; rowmin[t] = 0xFFFFFFFFu; }
}

// ---------------- kernel P2: bnorm (order-free) + emb->bf16 + zero counts --------------
__global__ void k_prepE(const float* __restrict__ emb, ushort* __restrict__ eh,
                        float* __restrict__ bnorm, unsigned* __restrict__ counts) {
    const int lane = threadIdx.x & 63;
    const int c = (blockIdx.x * blockDim.x + threadIdx.x) >> 6;   // 0..4095
    const float4* p = (const float4*)(emb + (size_t)c * DDIM);
    const float4 v0 = p[lane * 2], v1 = p[lane * 2 + 1];
    uint4 w; w.x = pack2(v0.x, v0.y); w.y = pack2(v0.z, v0.w);
    w.z = pack2(v1.x, v1.y); w.w = pack2(v1.z, v1.w);
    *(uint4*)(eh + (size_t)c * DDIM + lane * 8) = w;
    float s = v0.x*v0.x + v0.y*v0.y + v0.z*v0.z + v0.w*v0.w
            + v1.x*v1.x + v1.y*v1.y + v1.z*v1.z + v1.w*v1.w;
    #pragma unroll
    for (int m = 32; m; m >>= 1) s += __shfl_xor(s, m);
    if (lane == 0) { bnorm[c] = s; counts[c] = 0u; }
}

// ---------------- kernel 3: bf16 MFMA GEMM, templated epilogue ----------------
// grid (128, 32), block 256 = 4 waves (2x2 of 64x64). Tile 128x128, BK=32 (R8-verified).
// MODE 0: store s' = ee - 2*dot' as bf16 to sbuf[row][col]           (single-pass path)
// MODE 1: per-row atomicMin of s' (+1.0f-biased f32 bits)            (two-pass fallback)
// MODE 2: append codes with s' <= rowmin + MARGIN to candidate list  (two-pass fallback)
template <int MODE>
__global__ __launch_bounds__(256) void k_mfma(const ushort* __restrict__ zh,
                                              const ushort* __restrict__ eh,
                                              const float* __restrict__ bnorm,
                                              ushort* __restrict__ sbuf,
                                              unsigned* __restrict__ rowmin,
                                              unsigned* __restrict__ ccnt,
                                              unsigned* __restrict__ cand) {
    __shared__ ushort Ab[128 * 40];   // 40-ushort row stride (80B)
    __shared__ ushort Bb[128 * 40];
    const int tid = threadIdx.x;
    const int lane = tid & 63;
    const int w = tid >> 6;
    const int wrow = (w >> 1) * 64, wcol = (w & 1) * 64;
    const int rbase = blockIdx.x * 128, cbase = blockIdx.y * 128;
    const int srow = tid >> 1, shalf = tid & 1;       // staging: (row, 16-elem half)
    const int r16 = lane & 15, g4 = (lane >> 4) * 4;  // frag row/col, k-subgroup

    f32x4 acc[4][4];
    #pragma unroll
    for (int i = 0; i < 4; ++i)
        #pragma unroll
        for (int j = 0; j < 4; ++j) acc[i][j] = (f32x4){0.f, 0.f, 0.f, 0.f};

    for (int kb = 0; kb < DDIM; kb += 32) {
        const ushort* ga = zh + (size_t)(rbase + srow) * DDIM + kb + shalf * 16;
        const ushort* gb = eh + (size_t)(cbase + srow) * DDIM + kb + shalf * 16;
        const uint4 a0 = *(const uint4*)ga;
        const uint4 a1 = *(const uint4*)(ga + 8);
        const uint4 b0 = *(const uint4*)gb;
        const uint4 b1 = *(const uint4*)(gb + 8);
        __syncthreads();   // prior iteration's frag reads complete
        *(uint4*)&Ab[srow * 40 + shalf * 16]     = a0;
        *(uint4*)&Ab[srow * 40 + shalf * 16 + 8] = a1;
        *(uint4*)&Bb[srow * 40 + shalf * 16]     = b0;
        *(uint4*)&Bb[srow * 40 + shalf * 16 + 8] = b1;
        __syncthreads();   // tile visible
        bf16x8 af[4], bf[4];
        #pragma unroll
        for (int f = 0; f < 4; ++f) {
            const ushort* pa = &Ab[(wrow + f * 16 + r16) * 40 + g4];
            uint4 ta;
            *(uint2*)&ta.x = *(const uint2*)pa;            // k = g4..g4+3
            *(uint2*)&ta.z = *(const uint2*)(pa + 16);     // k = 16+g4..
            af[f] = *(bf16x8*)&ta;
            const ushort* pb = &Bb[(wcol + f * 16 + r16) * 40 + g4];
            uint4 tb;
            *(uint2*)&tb.x = *(const uint2*)pb;
            *(uint2*)&tb.z = *(const uint2*)(pb + 16);
            bf[f] = *(bf16x8*)&tb;
        }
        #pragma unroll
        for (int fi = 0; fi < 4; ++fi)
            #pragma unroll
            for (int fj = 0; fj < 4; ++fj)
                acc[fi][fj] = __builtin_amdgcn_mfma_f32_16x16x32_bf16(
                    af[fi], bf[fj], acc[fi][fj], 0, 0, 0);
    }

    // C/D layout: value (fi,fj,r) -> row = wrow+fi*16+g4+r, col = wcol+fj*16+r16
    float bn[4];
    #pragma unroll
    for (int fj = 0; fj < 4; ++fj) bn[fj] = bnorm[cbase + wcol + fj * 16 + r16];

    if (MODE == 0) {
        #pragma unroll
        for (int fi = 0; fi < 4; ++fi) {
            #pragma unroll
            for (int r = 0; r < 4; ++r) {
                ushort* sp = sbuf + (size_t)(rbase + wrow + fi * 16 + g4 + r) * NE
                           + cbase + wcol + r16;
                #pragma unroll
                for (int fj = 0; fj < 4; ++fj)
                    sp[fj * 16] = f2bf(fmaf(-2.f, acc[fi][fj][r], bn[fj]));
            }
        }
    } else if (MODE == 1) {
        #pragma unroll
        for (int fi = 0; fi < 4; ++fi) {
            #pragma unroll
            for (int r = 0; r < 4; ++r) {
                float m = INFINITY;
                #pragma unroll
                for (int fj = 0; fj < 4; ++fj)
                    m = fminf(m, fmaf(-2.f, acc[fi][fj][r], bn[fj]));
                #pragma unroll
                for (int x = 1; x < 16; x <<= 1) m = fminf(m, __shfl_xor(m, x));
                if (r16 == 0)
                    atomicMin(&rowmin[rbase + wrow + fi * 16 + g4 + r],
                              __float_as_uint(m + 1.0f));   // s' in ±0.04 -> biased positive
            }
        }
    } else {
        #pragma unroll
        for (int fi = 0; fi < 4; ++fi) {
            #pragma unroll
            for (int r = 0; r < 4; ++r) {
                const int row = rbase + wrow + fi * 16 + g4 + r;
                const float thr = __uint_as_float(rowmin[row]) - 1.0f + MARGIN;
                #pragma unroll
                for (int fj = 0; fj < 4; ++fj) {
                    const float s = fmaf(-2.f, acc[fi][fj][r], bn[fj]);
                    if (s <= thr) {
                        const unsigned slot = atomicAdd(&ccnt[row], 1u);
                        if (slot < MAXC)
                            cand[(size_t)row * MAXC + slot] =
                                (unsigned)(cbase + wcol + fj * 16 + r16);
                    }
                }
            }
        }
    }
}

// ---------------- kernel 4 (path A): scan sbuf -> per-row min + candidates -------------
// one wave per row; lane holds 64 bf16 s' values in 8 uint4 regs; no re-read.
__global__ void k_pick(const ushort* __restrict__ sbuf, unsigned* __restrict__ ccnt,
                       unsigned* __restrict__ cand) {
    const int lane = threadIdx.x & 63;
    const int row = blockIdx.x * 4 + (threadIdx.x >> 6);
    const uint4* p = (const uint4*)(sbuf + (size_t)row * NE);
    uint4 v[8];
    #pragma unroll
    for (int j = 0; j < 8; ++j) v[j] = p[j * 64 + lane];   // 1KB contiguous per instr
    float mn = INFINITY;
    #pragma unroll
    for (int j = 0; j < 8; ++j) {
        const unsigned* u = (const unsigned*)&v[j];
        #pragma unroll
        for (int q = 0; q < 4; ++q) {
            mn = fminf(mn, __uint_as_float(u[q] << 16));
            mn = fminf(mn, __uint_as_float(u[q] & 0xffff0000u));
        }
    }
    #pragma unroll
    for (int m = 32; m; m >>= 1) mn = fminf(mn, __shfl_xor(mn, m));
    const float thr = mn + MARGIN;
    #pragma unroll
    for (int j = 0; j < 8; ++j) {
        const unsigned* u = (const unsigned*)&v[j];
        #pragma unroll
        for (int q = 0; q < 4; ++q) {
            const int col0 = j * 512 + lane * 8 + q * 2;
            if (__uint_as_float(u[q] << 16) <= thr) {
                const unsigned slot = atomicAdd(&ccnt[row], 1u);
                if (slot < MAXC) cand[(size_t)row * MAXC + slot] = (unsigned)col0;
            }
            if (__uint_as_float(u[q] & 0xffff0000u) <= thr) {
                const unsigned slot = atomicAdd(&ccnt[row], 1u);
                if (slot < MAXC) cand[(size_t)row * MAXC + slot] = (unsigned)(col0 + 1);
            }
        }
    }
}

// ---------------- exact numpy chain: sequential ascending-k FMA + exact bucketing ------
__device__ __forceinline__ unsigned long long exact_key(const float4* __restrict__ zp4,
                                                        const float* __restrict__ emb,
                                                        const float* __restrict__ bnorm,
                                                        float zn, int c) {
    const float4* ep4 = (const float4*)(emb + (size_t)c * DDIM);
    float acc = 0.f;
    #pragma unroll 8
    for (int q = 0; q < DDIM / 4; ++q) {
        const float4 zv = zp4[q];
        const float4 ev = ep4[q];
        acc = fmaf(zv.x, ev.x, acc);
        acc = fmaf(zv.y, ev.y, acc);
        acc = fmaf(zv.z, ev.z, acc);
        acc = fmaf(zv.w, ev.w, acc);
    }
    const float s = __fsub_rn(__fadd_rn(zn, bnorm[c]), __fmul_rn(2.f, acc));
    return ((unsigned long long)__float_as_uint(s) << 32) | (unsigned)c;
}

// ---------------- kernel 5: exact per-candidate resolve ----------------
__global__ void k_exact(const unsigned* __restrict__ ccnt, const unsigned* __restrict__ cand,
                        const float* __restrict__ z, const float* __restrict__ emb,
                        const float* __restrict__ znorm, const float* __restrict__ bnorm,
                        int* __restrict__ idxbuf) {
    const int lane = threadIdx.x & 63;
    const int row = blockIdx.x * 4 + (threadIdx.x >> 6);
    const int cnt = (int)ccnt[row];
    if (cnt == 1) {          // unique candidate == exact winner
        if (lane == 0) idxbuf[row] = (int)cand[(size_t)row * MAXC];
        return;
    }
    const float zn = znorm[row];
    const float4* zp4 = (const float4*)(z + (size_t)row * DDIM);
    unsigned long long best = ~0ULL;
    if (cnt <= MAXC) {
        if (lane < cnt)
            best = exact_key(zp4, emb, bnorm, zn, (int)cand[(size_t)row * MAXC + lane]);
    } else {                 // overflow fallback (never expected): exact scan of all codes
        for (int c = lane; c < NE; c += 64) {
            const unsigned long long k = exact_key(zp4, emb, bnorm, zn, c);
            if (k < best) best = k;
        }
    }
    #pragma unroll
    for (int m = 32; m; m >>= 1) {
        const unsigned long long ov = __shfl_xor(best, m);
        if (ov < best) best = ov;
    }
    if (lane == 0) idxbuf[row] = (int)(best & 0xffffffffu);
}

// ---------------- kernel 6: gather + STE + counts + loss partials ----------------
__global__ void k_gather(const float* __restrict__ z, const float* __restrict__ emb,
                         const int* __restrict__ idxbuf, float* __restrict__ out,
                         unsigned* __restrict__ counts, float* __restrict__ d2buf) {
    const int lane = threadIdx.x & 63;
    const int row = blockIdx.x * 4 + (threadIdx.x >> 6);
    const int id = idxbuf[row];

    const float* ep = emb + (size_t)id * DDIM;
    const float* zp = z + (size_t)row * DDIM;
    float* op = out + 1 + (size_t)row * DDIM;
    float d2 = 0.f;
    #pragma unroll
    for (int m = 0; m < 8; ++m) {
        const int k = m * 64 + lane;
        const float e = ep[k];
        const float zv = zp[k];
        const float t = e - zv;          // two-step rounding matches reference STE
        op[k] = zv + t;
        d2 = fmaf(t, t, d2);
    }
    #pragma unroll
    for (int m = 32; m; m >>= 1) d2 += __shfl_xor(d2, m);
    if (lane == 0) {
        atomicAdd(&counts[id], 1u);
        d2buf[row] = d2;
        out[1 + (size_t)NZ + row] = (float)id;
    }
}

// ---------------- kernel 7: finalize loss + perplexity ----------------
__global__ void k_final(const float* __restrict__ d2buf, const unsigned* __restrict__ counts,
                        float* __restrict__ out) {
    __shared__ double sh[256];
    __shared__ float  shf[256];
    const int tid = threadIdx.x;
    double ent = 0.0;
    for (int i = tid; i < NE; i += 256) {
        const double p = (double)counts[i] / (double)NROWS;
        ent += p * log(p + 1e-10);
    }
    float sse = 0.f;
    for (int i = tid; i < NROWS; i += 256) sse += d2buf[i];
    sh[tid] = ent; shf[tid] = sse;
    __syncthreads();
    for (int s = 128; s; s >>= 1) {
        if (tid < s) { sh[tid] += sh[tid + s]; shf[tid] += shf[tid + s]; }
        __syncthreads();
    }
    if (tid == 0) {
        out[0] = 1.25f * (shf[0] / (float)NZ);
        out[1 + (size_t)NZ + NROWS] = (float)exp(-sh[0]);
    }
}

extern "C" void kernel_launch(void* const* d_in, const int* in_sizes, int n_in,
                              void* d_out, int out_size, void* d_ws, size_t ws_size,
                              hipStream_t stream) {
    const float* z   = (const float*)d_in[0];
    const float* emb = (const float*)d_in[1];
    float* out = (float*)d_out;
    char* ws = (char*)d_ws;

    // big intermediates live inside out[1..NZ] (k_gather overwrites them afterwards)
    ushort*   zh   = (ushort*)(out + 4);                       // 16 MB
    ushort*   eh   = (ushort*)(out + 4 + 4194304);             //  4 MB
    unsigned* cand = (unsigned*)(out + 4 + 4194304 + 1048576); //  2 MB

    size_t off = 0;
    float*    bnorm  = (float*)(ws + off); off += (size_t)NE * 4;          // 16KB
    unsigned* counts = (unsigned*)(ws + off); off += (size_t)NE * 4;       // 16KB
    float*    d2buf  = (float*)(ws + off); off += (size_t)NROWS * 4;       // 64KB
    float*    znorm  = (float*)(ws + off); off += (size_t)NROWS * 4;       // 64KB
    int*      idxbuf = (int*)(ws + off); off += (size_t)NROWS * 4;         // 64KB
    unsigned* rowmin = (unsigned*)(ws + off); off += (size_t)NROWS * 4;    // 64KB
    unsigned* ccnt   = (unsigned*)(ws + off); off += (size_t)NROWS * 4;    // 64KB
    ushort*   sbuf   = (ushort*)(ws + off);
    const bool bigws = ws_size >= off + (size_t)NROWS * NE * 2;            // +128MB

    k_prepZ<<<256, 256, 0, stream>>>(z, zh, znorm, ccnt, rowmin);
    k_prepE<<<1024, 256, 0, stream>>>(emb, eh, bnorm, counts);
    if (bigws) {
        k_mfma<0><<<dim3(NROWS / 128, NE / 128), 256, 0, stream>>>(zh, eh, bnorm,
                                                                   sbuf, rowmin, ccnt, cand);
        k_pick<<<NROWS / 4, 256, 0, stream>>>(sbuf, ccnt, cand);
    } else {
        k_mfma<1><<<dim3(NROWS / 128, NE / 128), 256, 0, stream>>>(zh, eh, bnorm,
                                                                   sbuf, rowmin, ccnt, cand);
        k_mfma<2><<<dim3(NROWS / 128, NE / 128), 256, 0, stream>>>(zh, eh, bnorm,
                                                                   sbuf, rowmin, ccnt, cand);
    }
    k_exact<<<NROWS / 4, 256, 0, stream>>>(ccnt, cand, z, emb, znorm, bnorm, idxbuf);
    k_gather<<<NROWS / 4, 256, 0, stream>>>(z, emb, idxbuf, out, counts, d2buf);
    k_final<<<1, 256, 0, stream>>>(d2buf, counts, out);
}

// Round 12
// 296.309 us; speedup vs baseline: 9.9706x; 1.1462x over previous
//
#include <hip/hip_runtime.h>
#include <math.h>

#define NROWS 16384      // 32*512
#define DDIM  512
#define NE    4096
#define NZ    (NROWS * DDIM)
#define MAXC  32             // per-row candidate cap (expected ~2.1)
#define MARGIN 2e-3f         // >= bound 2E + bucket + 2*bf16store = 1.39e-3

typedef __attribute__((ext_vector_type(8))) short bf16x8;
typedef __attribute__((ext_vector_type(4))) float f32x4;

__device__ __forceinline__ float sqr_rn(float x) { return __fmul_rn(x, x); }
__device__ __forceinline__ ushort f2bf(float f) {   // RNE f32->bf16
    const unsigned u = __float_as_uint(f);
    return (ushort)((u + 0x7fffu + ((u >> 16) & 1u)) >> 16);
}
__device__ __forceinline__ unsigned pack2(float a, float b) {
    return (unsigned)f2bf(a) | ((unsigned)f2bf(b) << 16);
}

// ---------------- kernel P1: numpy-exact znorm + z->bf16 ----------------
__global__ void k_prepZ(const float* __restrict__ z, ushort* __restrict__ zh,
                        float* __restrict__ znorm) {
    const int t = blockIdx.x * blockDim.x + threadIdx.x;   // 0 .. 65535
    const int row = t >> 2, blk = t & 3;
    const float4* p = (const float4*)(z + (size_t)row * DDIM + blk * 128);
    ushort* zo = zh + (size_t)row * DDIM + blk * 128;
    float4 v0 = p[0], v1 = p[1];
    {
        uint4 w; w.x = pack2(v0.x, v0.y); w.y = pack2(v0.z, v0.w);
        w.z = pack2(v1.x, v1.y); w.w = pack2(v1.z, v1.w);
        *(uint4*)zo = w;
    }
    float r[8];
    r[0] = sqr_rn(v0.x); r[1] = sqr_rn(v0.y); r[2] = sqr_rn(v0.z); r[3] = sqr_rn(v0.w);
    r[4] = sqr_rn(v1.x); r[5] = sqr_rn(v1.y); r[6] = sqr_rn(v1.z); r[7] = sqr_rn(v1.w);
    #pragma unroll
    for (int i = 1; i < 16; ++i) {
        v0 = p[2 * i]; v1 = p[2 * i + 1];
        uint4 w; w.x = pack2(v0.x, v0.y); w.y = pack2(v0.z, v0.w);
        w.z = pack2(v1.x, v1.y); w.w = pack2(v1.z, v1.w);
        *(uint4*)(zo + i * 8) = w;
        r[0] = __fadd_rn(r[0], sqr_rn(v0.x)); r[1] = __fadd_rn(r[1], sqr_rn(v0.y));
        r[2] = __fadd_rn(r[2], sqr_rn(v0.z)); r[3] = __fadd_rn(r[3], sqr_rn(v0.w));
        r[4] = __fadd_rn(r[4], sqr_rn(v1.x)); r[5] = __fadd_rn(r[5], sqr_rn(v1.y));
        r[6] = __fadd_rn(r[6], sqr_rn(v1.z)); r[7] = __fadd_rn(r[7], sqr_rn(v1.w));
    }
    const float B = __fadd_rn(__fadd_rn(__fadd_rn(r[0], r[1]), __fadd_rn(r[2], r[3])),
                              __fadd_rn(__fadd_rn(r[4], r[5]), __fadd_rn(r[6], r[7])));
    const float s01 = __fadd_rn(B, __shfl_xor(B, 1));     // (B0+B1)/(B2+B3), in-wave
    const float zn  = __fadd_rn(s01, __shfl_xor(s01, 2)); // ((B0+B1)+(B2+B3))
    if (blk == 0) znorm[row] = zn;
}

// ---------------- kernel P2: bnorm (order-free) + emb->bf16 + zero counts --------------
__global__ void k_prepE(const float* __restrict__ emb, ushort* __restrict__ eh,
                        float* __restrict__ bnorm, unsigned* __restrict__ counts) {
    const int lane = threadIdx.x & 63;
    const int c = (blockIdx.x * blockDim.x + threadIdx.x) >> 6;   // 0..4095
    const float4* p = (const float4*)(emb + (size_t)c * DDIM);
    const float4 v0 = p[lane * 2], v1 = p[lane * 2 + 1];
    uint4 w; w.x = pack2(v0.x, v0.y); w.y = pack2(v0.z, v0.w);
    w.z = pack2(v1.x, v1.y); w.w = pack2(v1.z, v1.w);
    *(uint4*)(eh + (size_t)c * DDIM + lane * 8) = w;
    float s = v0.x*v0.x + v0.y*v0.y + v0.z*v0.z + v0.w*v0.w
            + v1.x*v1.x + v1.y*v1.y + v1.z*v1.z + v1.w*v1.w;
    #pragma unroll
    for (int m = 32; m; m >>= 1) s += __shfl_xor(s, m);
    if (lane == 0) { bnorm[c] = s; counts[c] = 0u; }
}

// ---------------- kernel 3: bf16 MFMA GEMM, fragment-native LDS ----------------
// grid (128, 32), block 256 = 4 waves (2x2 of 64x64). Tile 128x128, BK=32.
// LDS holds fragments directly: chunk g (16 rows) = [64 lanes][8 bf16]; frag load is one
// clean ds_read_b128/lane. Fragment CONTENT identical to the R8/R9-verified build:
// lane l of chunk g holds rows 16g+(l&15), k = kb+4*(l>>4)+{0..3} then kb+16+4*(l>>4)+{0..3}.
// Epilogue: s' = ee - 2*dot' stored bf16, 64-col-block permuted (in-block idx = r16*4+fj),
// packed uint2 per lane -> 128B coalesced segments. k_pick decodes.
__global__ __launch_bounds__(256) void k_mfma(const ushort* __restrict__ zh,
                                              const ushort* __restrict__ eh,
                                              const float* __restrict__ bnorm,
                                              ushort* __restrict__ sbuf) {
    __shared__ ushort Af[8 * 512];   // 8 chunks x 64 lanes x 8 ushort = 8KB
    __shared__ ushort Bf[8 * 512];
    const int tid = threadIdx.x;
    const int lane = tid & 63;
    const int w = tid >> 6;
    const int wrow = (w >> 1) * 64, wcol = (w & 1) * 64;
    const int rbase = blockIdx.x * 128, cbase = blockIdx.y * 128;
    const int sr = tid >> 1, sh = tid & 1;            // staging: row 0..127, k-half 0..1
    const int g  = sr >> 4, r15 = sr & 15;            // staging chunk, row-in-chunk
    const int r16 = lane & 15, g4 = (lane >> 4) * 4;  // frag row/col, k-subgroup

    f32x4 acc[4][4];
    #pragma unroll
    for (int i = 0; i < 4; ++i)
        #pragma unroll
        for (int j = 0; j < 4; ++j) acc[i][j] = (f32x4){0.f, 0.f, 0.f, 0.f};

    for (int kb = 0; kb < DDIM; kb += 32) {
        // load 16 bf16 (32B) of A and B per thread: k = kb+16*sh .. +15
        const ushort* ga = zh + (size_t)(rbase + sr) * DDIM + kb + sh * 16;
        const ushort* gb = eh + (size_t)(cbase + sr) * DDIM + kb + sh * 16;
        const uint4 qa0 = *(const uint4*)ga;          // k-offsets 0..7  (within half)
        const uint4 qa1 = *(const uint4*)(ga + 8);    // k-offsets 8..15
        const uint4 qb0 = *(const uint4*)gb;
        const uint4 qb1 = *(const uint4*)(gb + 8);
        __syncthreads();   // prior iteration's frag reads complete
        // scatter to fragment layout: jj-th 4-group -> lane r15+16jj, ushort-quad sh
        {
            ushort* pa = &Af[g * 512 + r15 * 8 + sh * 4];
            *(uint2*)(pa +   0) = make_uint2(qa0.x, qa0.y);   // jj=0
            *(uint2*)(pa + 128) = make_uint2(qa0.z, qa0.w);   // jj=1 (+16 lanes * 8)
            *(uint2*)(pa + 256) = make_uint2(qa1.x, qa1.y);   // jj=2
            *(uint2*)(pa + 384) = make_uint2(qa1.z, qa1.w);   // jj=3
            ushort* pb = &Bf[g * 512 + r15 * 8 + sh * 4];
            *(uint2*)(pb +   0) = make_uint2(qb0.x, qb0.y);
            *(uint2*)(pb + 128) = make_uint2(qb0.z, qb0.w);
            *(uint2*)(pb + 256) = make_uint2(qb1.x, qb1.y);
            *(uint2*)(pb + 384) = make_uint2(qb1.z, qb1.w);
        }
        __syncthreads();   // tile visible
        bf16x8 af[4], bf[4];
        #pragma unroll
        for (int f = 0; f < 4; ++f) {
            af[f] = *(const bf16x8*)&Af[((wrow >> 4) + f) * 512 + lane * 8];  // ds_read_b128
            bf[f] = *(const bf16x8*)&Bf[((wcol >> 4) + f) * 512 + lane * 8];
        }
        #pragma unroll
        for (int fi = 0; fi < 4; ++fi)
            #pragma unroll
            for (int fj = 0; fj < 4; ++fj)
                acc[fi][fj] = __builtin_amdgcn_mfma_f32_16x16x32_bf16(
                    af[fi], bf[fj], acc[fi][fj], 0, 0, 0);
    }

    // C/D layout: value (fi,fj,r) -> row = wrow+fi*16+g4+r, col = wcol+fj*16+r16
    float bn[4];
    #pragma unroll
    for (int fj = 0; fj < 4; ++fj) bn[fj] = bnorm[cbase + wcol + fj * 16 + r16];

    #pragma unroll
    for (int fi = 0; fi < 4; ++fi) {
        #pragma unroll
        for (int r = 0; r < 4; ++r) {
            const int row = rbase + wrow + fi * 16 + g4 + r;
            float s[4];
            #pragma unroll
            for (int fj = 0; fj < 4; ++fj) s[fj] = fmaf(-2.f, acc[fi][fj][r], bn[fj]);
            uint2* sp = (uint2*)(sbuf + (size_t)row * NE + cbase + wcol);
            sp[r16] = make_uint2(pack2(s[0], s[1]), pack2(s[2], s[3]));
        }
    }
}

// ---------------- exact numpy chain: sequential ascending-k FMA + exact bucketing ------
__device__ __forceinline__ unsigned long long exact_key(const float4* __restrict__ zp4,
                                                        const float* __restrict__ emb,
                                                        const float* __restrict__ bnorm,
                                                        float zn, int c) {
    const float4* ep4 = (const float4*)(emb + (size_t)c * DDIM);
    float acc = 0.f;
    #pragma unroll 8
    for (int q = 0; q < DDIM / 4; ++q) {
        const float4 zv = zp4[q];
        const float4 ev = ep4[q];
        acc = fmaf(zv.x, ev.x, acc);
        acc = fmaf(zv.y, ev.y, acc);
        acc = fmaf(zv.z, ev.z, acc);
        acc = fmaf(zv.w, ev.w, acc);
    }
    const float s = __fsub_rn(__fadd_rn(zn, bnorm[c]), __fmul_rn(2.f, acc));
    return ((unsigned long long)__float_as_uint(s) << 32) | (unsigned)c;
}

// ---------------- kernel 4: fused scan + candidate pick + exact resolve ----------------
// one wave per row; candidates stay in per-wave LDS (never global -> no cross-block race).
// 64-col-block permuted sbuf layout: col = blk*64 + (i&3)*16 + (i>>2).
__global__ void k_pick(const ushort* __restrict__ sbuf, const float* __restrict__ z,
                       const float* __restrict__ emb, const float* __restrict__ znorm,
                       const float* __restrict__ bnorm, int* __restrict__ idxbuf) {
    __shared__ unsigned candL[4][MAXC];
    __shared__ unsigned cntL[4];
    const int lane = threadIdx.x & 63;
    const int w = threadIdx.x >> 6;
    const int row = blockIdx.x * 4 + w;
    if (threadIdx.x < 4) cntL[threadIdx.x] = 0u;
    __syncthreads();

    const uint4* p = (const uint4*)(sbuf + (size_t)row * NE);
    uint4 v[8];
    #pragma unroll
    for (int j = 0; j < 8; ++j) v[j] = p[j * 64 + lane];   // 1KB contiguous per instr
    float mn = INFINITY;
    #pragma unroll
    for (int j = 0; j < 8; ++j) {
        const unsigned* u = (const unsigned*)&v[j];
        #pragma unroll
        for (int q = 0; q < 4; ++q) {
            mn = fminf(mn, __uint_as_float(u[q] << 16));
            mn = fminf(mn, __uint_as_float(u[q] & 0xffff0000u));
        }
    }
    #pragma unroll
    for (int m = 32; m; m >>= 1) mn = fminf(mn, __shfl_xor(mn, m));
    const float thr = mn + MARGIN;
    #pragma unroll
    for (int j = 0; j < 8; ++j) {
        const unsigned* u = (const unsigned*)&v[j];
        #pragma unroll
        for (int q = 0; q < 4; ++q) {
            #pragma unroll
            for (int hi = 0; hi < 2; ++hi) {
                const float val = __uint_as_float(hi ? (u[q] & 0xffff0000u) : (u[q] << 16));
                if (val <= thr) {
                    const int pos = j * 512 + lane * 8 + q * 2 + hi;
                    const int inb = pos & 63;
                    const int col = (pos >> 6) * 64 + (inb & 3) * 16 + (inb >> 2);
                    const unsigned slot = atomicAdd(&cntL[w], 1u);
                    if (slot < MAXC) candL[w][slot] = (unsigned)col;
                }
            }
        }
    }
    __syncthreads();

    const int cnt = (int)cntL[w];
    int id;
    if (cnt == 1) {
        id = (int)(candL[w][0] & (NE - 1));
    } else {
        const float zn = znorm[row];
        const float4* zp4 = (const float4*)(z + (size_t)row * DDIM);
        unsigned long long best = ~0ULL;
        if (cnt >= 2 && cnt <= MAXC) {
            if (lane < cnt)
                best = exact_key(zp4, emb, bnorm, zn, (int)(candL[w][lane] & (NE - 1)));
        } else {             // cnt==0 (impossible) or overflow: exact scan of all codes
            for (int c = lane; c < NE; c += 64) {
                const unsigned long long k = exact_key(zp4, emb, bnorm, zn, c);
                if (k < best) best = k;
            }
        }
        #pragma unroll
        for (int m = 32; m; m >>= 1) {
            const unsigned long long ov = __shfl_xor(best, m);
            if (ov < best) best = ov;
        }
        id = (int)(__shfl(best, 0) & (unsigned long long)(NE - 1));
    }
    if (lane == 0) idxbuf[row] = id;
}

// ---------------- kernel 5: gather + STE + counts + loss partials ----------------
// reads ONLY idxbuf(ws)/z/emb; writes out -> no out read-write overlap anywhere.
__global__ void k_gather(const int* __restrict__ idxbuf, const float* __restrict__ z,
                         const float* __restrict__ emb, float* __restrict__ out,
                         unsigned* __restrict__ counts, float* __restrict__ d2buf) {
    const int lane = threadIdx.x & 63;
    const int row = blockIdx.x * 4 + (threadIdx.x >> 6);
    const int id = idxbuf[row] & (NE - 1);
    const float* zp = z + (size_t)row * DDIM;
    const float* ep = emb + (size_t)id * DDIM;
    float* op = out + 1 + (size_t)row * DDIM;
    float d2 = 0.f;
    #pragma unroll
    for (int m = 0; m < 8; ++m) {
        const int k = m * 64 + lane;
        const float e = ep[k];
        const float zv = zp[k];
        const float t = e - zv;          // two-step rounding matches reference STE
        op[k] = zv + t;
        d2 = fmaf(t, t, d2);
    }
    #pragma unroll
    for (int m = 32; m; m >>= 1) d2 += __shfl_xor(d2, m);
    if (lane == 0) {
        atomicAdd(&counts[id], 1u);
        d2buf[row] = d2;
        out[1 + (size_t)NZ + row] = (float)id;
    }
}

// ---------------- kernel 6: finalize loss + perplexity ----------------
__global__ void k_final(const float* __restrict__ d2buf, const unsigned* __restrict__ counts,
                        float* __restrict__ out) {
    __shared__ double sh[256];
    __shared__ float  shf[256];
    const int tid = threadIdx.x;
    double ent = 0.0;
    for (int i = tid; i < NE; i += 256) {
        const double p = (double)counts[i] / (double)NROWS;
        ent += p * log(p + 1e-10);
    }
    float sse = 0.f;
    for (int i = tid; i < NROWS; i += 256) sse += d2buf[i];
    sh[tid] = ent; shf[tid] = sse;
    __syncthreads();
    for (int s = 128; s; s >>= 1) {
        if (tid < s) { sh[tid] += sh[tid + s]; shf[tid] += shf[tid + s]; }
        __syncthreads();
    }
    if (tid == 0) {
        out[0] = 1.25f * (shf[0] / (float)NZ);
        out[1 + (size_t)NZ + NROWS] = (float)exp(-sh[0]);
    }
}

extern "C" void kernel_launch(void* const* d_in, const int* in_sizes, int n_in,
                              void* d_out, int out_size, void* d_ws, size_t ws_size,
                              hipStream_t stream) {
    const float* z   = (const float*)d_in[0];
    const float* emb = (const float*)d_in[1];
    float* out = (float*)d_out;
    char* ws = (char*)d_ws;

    // zh/eh live inside out[1..NZ]: written by prep kernels, read only by k_mfma,
    // and k_gather's out-writes come strictly later in stream order.
    ushort* zh = (ushort*)(out + 4);                       // 16 MB
    ushort* eh = (ushort*)(out + 4 + 4194304);             //  4 MB

    size_t off = 0;
    float*    bnorm  = (float*)(ws + off); off += (size_t)NE * 4;          // 16KB
    unsigned* counts = (unsigned*)(ws + off); off += (size_t)NE * 4;       // 16KB
    float*    d2buf  = (float*)(ws + off); off += (size_t)NROWS * 4;       // 64KB
    float*    znorm  = (float*)(ws + off); off += (size_t)NROWS * 4;       // 64KB
    int*      idxbuf = (int*)(ws + off); off += (size_t)NROWS * 4;         // 64KB
    ushort*   sbuf   = (ushort*)(ws + off);                                // 128MB (fits: R9 bigws check)

    k_prepZ<<<256, 256, 0, stream>>>(z, zh, znorm);
    k_prepE<<<1024, 256, 0, stream>>>(emb, eh, bnorm, counts);
    k_mfma<<<dim3(NROWS / 128, NE / 128), 256, 0, stream>>>(zh, eh, bnorm, sbuf);
    k_pick<<<NROWS / 4, 256, 0, stream>>>(sbuf, z, emb, znorm, bnorm, idxbuf);
    k_gather<<<NROWS / 4, 256, 0, stream>>>(idxbuf, z, emb, out, counts, d2buf);
    k_final<<<1, 256, 0, stream>>>(d2buf, counts, out);
}

// Round 13
// 292.658 us; speedup vs baseline: 10.0950x; 1.0125x over previous
//
#include <hip/hip_runtime.h>
#include <math.h>

#define NROWS 16384      // 32*512
#define DDIM  512
#define NE    4096
#define NZ    (NROWS * DDIM)
#define MAXC  64             // per-row candidate cap (expected ~2.1)
#define MARGIN 2e-3f         // >= bound 2E + bucket + bf16 rounds ~ 1.4e-3

typedef __attribute__((ext_vector_type(8))) short bf16x8;
typedef __attribute__((ext_vector_type(4))) float f32x4;

__device__ __forceinline__ float sqr_rn(float x) { return __fmul_rn(x, x); }
__device__ __forceinline__ ushort f2bf(float f) {   // RNE f32->bf16
    const unsigned u = __float_as_uint(f);
    return (ushort)((u + 0x7fffu + ((u >> 16) & 1u)) >> 16);
}
__device__ __forceinline__ unsigned pack2(float a, float b) {
    return (unsigned)f2bf(a) | ((unsigned)f2bf(b) << 16);
}
// async global->LDS, 16B/lane; LDS dest = wave-uniform base + lane*16
__device__ __forceinline__ void glds16(const void* g, void* l) {
    __builtin_amdgcn_global_load_lds(
        (const __attribute__((address_space(1))) unsigned int*)g,
        (__attribute__((address_space(3))) unsigned int*)l, 16, 0, 0);
}

// ---------------- kernel 1: fused prep (Z: numpy-exact znorm + bf16; E: bnorm + bf16) --
__global__ void k_prep(const float* __restrict__ z, const float* __restrict__ emb,
                       ushort* __restrict__ zh, ushort* __restrict__ eh,
                       float* __restrict__ znorm, float* __restrict__ bnorm,
                       unsigned* __restrict__ counts) {
    if (blockIdx.x < 1024) {            // ---- E role: 4096 codes x 1 wave
        const int lane = threadIdx.x & 63;
        const int c = (int)((blockIdx.x * 256 + threadIdx.x) >> 6);
        const float4* p = (const float4*)(emb + (size_t)c * DDIM);
        const float4 v0 = p[lane * 2], v1 = p[lane * 2 + 1];
        uint4 w; w.x = pack2(v0.x, v0.y); w.y = pack2(v0.z, v0.w);
        w.z = pack2(v1.x, v1.y); w.w = pack2(v1.z, v1.w);
        *(uint4*)(eh + (size_t)c * DDIM + lane * 8) = w;
        float s = v0.x*v0.x + v0.y*v0.y + v0.z*v0.z + v0.w*v0.w
                + v1.x*v1.x + v1.y*v1.y + v1.z*v1.z + v1.w*v1.w;
        #pragma unroll
        for (int m = 32; m; m >>= 1) s += __shfl_xor(s, m);
        if (lane == 0) { bnorm[c] = s; counts[c] = 0u; }
    } else {                            // ---- Z role: numpy-exact pairwise znorm
        const int t = (int)((blockIdx.x - 1024) * 256 + threadIdx.x);   // 0..65535
        const int row = t >> 2, blk = t & 3;
        const float4* p = (const float4*)(z + (size_t)row * DDIM + blk * 128);
        ushort* zo = zh + (size_t)row * DDIM + blk * 128;
        float4 v0 = p[0], v1 = p[1];
        {
            uint4 w; w.x = pack2(v0.x, v0.y); w.y = pack2(v0.z, v0.w);
            w.z = pack2(v1.x, v1.y); w.w = pack2(v1.z, v1.w);
            *(uint4*)zo = w;
        }
        float r[8];
        r[0] = sqr_rn(v0.x); r[1] = sqr_rn(v0.y); r[2] = sqr_rn(v0.z); r[3] = sqr_rn(v0.w);
        r[4] = sqr_rn(v1.x); r[5] = sqr_rn(v1.y); r[6] = sqr_rn(v1.z); r[7] = sqr_rn(v1.w);
        #pragma unroll
        for (int i = 1; i < 16; ++i) {
            v0 = p[2 * i]; v1 = p[2 * i + 1];
            uint4 w; w.x = pack2(v0.x, v0.y); w.y = pack2(v0.z, v0.w);
            w.z = pack2(v1.x, v1.y); w.w = pack2(v1.z, v1.w);
            *(uint4*)(zo + i * 8) = w;
            r[0] = __fadd_rn(r[0], sqr_rn(v0.x)); r[1] = __fadd_rn(r[1], sqr_rn(v0.y));
            r[2] = __fadd_rn(r[2], sqr_rn(v0.z)); r[3] = __fadd_rn(r[3], sqr_rn(v0.w));
            r[4] = __fadd_rn(r[4], sqr_rn(v1.x)); r[5] = __fadd_rn(r[5], sqr_rn(v1.y));
            r[6] = __fadd_rn(r[6], sqr_rn(v1.z)); r[7] = __fadd_rn(r[7], sqr_rn(v1.w));
        }
        const float B = __fadd_rn(__fadd_rn(__fadd_rn(r[0], r[1]), __fadd_rn(r[2], r[3])),
                                  __fadd_rn(__fadd_rn(r[4], r[5]), __fadd_rn(r[6], r[7])));
        const float s01 = __fadd_rn(B, __shfl_xor(B, 1));     // in-wave quad reduce
        const float zn  = __fadd_rn(s01, __shfl_xor(s01, 2)); // ((B0+B1)+(B2+B3))
        if (blk == 0) znorm[row] = zn;
    }
}

// ---------------- kernel 2: bf16 MFMA GEMM via global_load_lds ----------------
// grid (128, 32), block 256 = 4 waves (2x2 of 64x64). Tile 128x128, BK=32.
// Fragment layout (contiguous-k): chunk g = 16 rows; lane l holds row 16g+(l&15),
// k = kb + 8*(l>>4) + {0..7} -> one contiguous 16B global chunk == gload_lds's
// lane-linear LDS write. SAME k-permutation for A and B => dot preserved.
// Epilogue: s' = ee - 2*dot' -> bf16 sbuf (64-col-block permuted, idx = r16*4+fj)
// + per-(row, 64-col-block) f32 min (each slot owned by one wave; no atomics).
template <int USE_BLK>
__global__ __launch_bounds__(256) void k_mfma(const ushort* __restrict__ zh,
                                              const ushort* __restrict__ eh,
                                              const float* __restrict__ bnorm,
                                              ushort* __restrict__ sbuf,
                                              float* __restrict__ rowblkmin) {
    __shared__ ushort Af[8 * 512];   // 8 chunks x 64 lanes x 8 ushort = 8KB
    __shared__ ushort Bf[8 * 512];
    const int tid = threadIdx.x;
    const int lane = tid & 63;
    const int w = tid >> 6;
    const int wrow = (w >> 1) * 64, wcol = (w & 1) * 64;
    const int rbase = blockIdx.x * 128, cbase = blockIdx.y * 128;
    const int r16 = lane & 15, g4 = (lane >> 4) * 4;
    const int k8 = (lane >> 4) * 8;
    const int c0 = 2 * w, c1 = c0 + 1;     // this wave stages chunks c0,c1 of A and B

    const ushort* gA0 = zh + (size_t)(rbase + 16 * c0 + r16) * DDIM + k8;
    const ushort* gA1 = zh + (size_t)(rbase + 16 * c1 + r16) * DDIM + k8;
    const ushort* gB0 = eh + (size_t)(cbase + 16 * c0 + r16) * DDIM + k8;
    const ushort* gB1 = eh + (size_t)(cbase + 16 * c1 + r16) * DDIM + k8;
    ushort* lA0 = &Af[c0 * 512]; ushort* lA1 = &Af[c1 * 512];
    ushort* lB0 = &Bf[c0 * 512]; ushort* lB1 = &Bf[c1 * 512];

    f32x4 acc[4][4];
    #pragma unroll
    for (int i = 0; i < 4; ++i)
        #pragma unroll
        for (int j = 0; j < 4; ++j) acc[i][j] = (f32x4){0.f, 0.f, 0.f, 0.f};

    for (int kb = 0; kb < DDIM; kb += 32) {
        __syncthreads();                 // prior iteration's frag reads complete
        glds16(gA0 + kb, lA0);
        glds16(gA1 + kb, lA1);
        glds16(gB0 + kb, lB0);
        glds16(gB1 + kb, lB1);
        __syncthreads();                 // compiler drains vmcnt before s_barrier
        bf16x8 af[4], bf[4];
        #pragma unroll
        for (int f = 0; f < 4; ++f) {
            af[f] = *(const bf16x8*)&Af[((wrow >> 4) + f) * 512 + lane * 8];  // b128, conflict-free
            bf[f] = *(const bf16x8*)&Bf[((wcol >> 4) + f) * 512 + lane * 8];
        }
        #pragma unroll
        for (int fi = 0; fi < 4; ++fi)
            #pragma unroll
            for (int fj = 0; fj < 4; ++fj)
                acc[fi][fj] = __builtin_amdgcn_mfma_f32_16x16x32_bf16(
                    af[fi], bf[fj], acc[fi][fj], 0, 0, 0);
    }

    // C/D layout: value (fi,fj,r) -> row = wrow+fi*16+g4+r, col = wcol+fj*16+r16
    float bn[4];
    #pragma unroll
    for (int fj = 0; fj < 4; ++fj) bn[fj] = bnorm[cbase + wcol + fj * 16 + r16];

    #pragma unroll
    for (int fi = 0; fi < 4; ++fi) {
        #pragma unroll
        for (int r = 0; r < 4; ++r) {
            const int row = rbase + wrow + fi * 16 + g4 + r;
            float s[4];
            #pragma unroll
            for (int fj = 0; fj < 4; ++fj) s[fj] = fmaf(-2.f, acc[fi][fj][r], bn[fj]);
            uint2* sp = (uint2*)(sbuf + (size_t)row * NE + cbase + wcol);
            sp[r16] = make_uint2(pack2(s[0], s[1]), pack2(s[2], s[3]));
            if (USE_BLK) {
                float m = fminf(fminf(s[0], s[1]), fminf(s[2], s[3]));
                #pragma unroll
                for (int x = 1; x < 16; x <<= 1) m = fminf(m, __shfl_xor(m, x));
                if (r16 == 0)
                    rowblkmin[(size_t)row * 64 + blockIdx.y * 2 + (w & 1)] = m;
            }
        }
    }
}

// ---------------- exact numpy chain: sequential ascending-k FMA + exact bucketing ------
__device__ __forceinline__ unsigned long long exact_key(const float4* __restrict__ zp4,
                                                        const float* __restrict__ emb,
                                                        const float* __restrict__ bnorm,
                                                        float zn, int c) {
    const float4* ep4 = (const float4*)(emb + (size_t)c * DDIM);
    float acc = 0.f;
    #pragma unroll 8
    for (int q = 0; q < DDIM / 4; ++q) {
        const float4 zv = zp4[q];
        const float4 ev = ep4[q];
        acc = fmaf(zv.x, ev.x, acc);
        acc = fmaf(zv.y, ev.y, acc);
        acc = fmaf(zv.z, ev.z, acc);
        acc = fmaf(zv.w, ev.w, acc);
    }
    const float s = __fsub_rn(__fadd_rn(zn, bnorm[c]), __fmul_rn(2.f, acc));
    return ((unsigned long long)__float_as_uint(s) << 32) | (unsigned)c;
}

// ---------------- kernel 3: fused pick + exact resolve + gather + STE ----------------
// one wave per row; candidates only in per-wave LDS; reads ws/inputs, writes out.
// sbuf in-64-block permutation: col = b*64 + (i&3)*16 + (i>>2).
template <int GUIDED>
__global__ void k_pg(const ushort* __restrict__ sbuf, const float* __restrict__ rowblkmin,
                     const float* __restrict__ z, const float* __restrict__ emb,
                     const float* __restrict__ znorm, const float* __restrict__ bnorm,
                     float* __restrict__ out, unsigned* __restrict__ counts,
                     float* __restrict__ d2buf) {
    __shared__ int candL[4][MAXC];
    __shared__ unsigned cntL[4];
    const int lane = threadIdx.x & 63;
    const int w = threadIdx.x >> 6;
    const int row = blockIdx.x * 4 + w;
    if (threadIdx.x < 4) cntL[threadIdx.x] = 0u;
    __syncthreads();

    if (GUIDED) {
        const float bm = rowblkmin[(size_t)row * 64 + lane];
        float gmin = bm;
        #pragma unroll
        for (int m = 32; m; m >>= 1) gmin = fminf(gmin, __shfl_xor(gmin, m));
        const float thr = gmin + MARGIN;
        unsigned long long bmask = __ballot(bm <= thr);   // expected ~1.1 blocks
        while (bmask) {
            const int b = __builtin_ctzll(bmask); bmask &= bmask - 1;
            const float val = __uint_as_float(
                (unsigned)sbuf[(size_t)row * NE + b * 64 + lane] << 16);
            if (val <= thr) {
                const unsigned slot = atomicAdd(&cntL[w], 1u);
                if (slot < MAXC)
                    candL[w][slot] = b * 64 + (lane & 3) * 16 + (lane >> 2);
            }
        }
    } else {
        const uint4* p = (const uint4*)(sbuf + (size_t)row * NE);
        uint4 v[8];
        #pragma unroll
        for (int j = 0; j < 8; ++j) v[j] = p[j * 64 + lane];
        float mn = INFINITY;
        #pragma unroll
        for (int j = 0; j < 8; ++j) {
            const unsigned* u = (const unsigned*)&v[j];
            #pragma unroll
            for (int q = 0; q < 4; ++q) {
                mn = fminf(mn, __uint_as_float(u[q] << 16));
                mn = fminf(mn, __uint_as_float(u[q] & 0xffff0000u));
            }
        }
        #pragma unroll
        for (int m = 32; m; m >>= 1) mn = fminf(mn, __shfl_xor(mn, m));
        const float thr = mn + MARGIN;
        #pragma unroll
        for (int j = 0; j < 8; ++j) {
            const unsigned* u = (const unsigned*)&v[j];
            #pragma unroll
            for (int q = 0; q < 4; ++q) {
                #pragma unroll
                for (int hi = 0; hi < 2; ++hi) {
                    const float val = __uint_as_float(hi ? (u[q] & 0xffff0000u)
                                                        : (u[q] << 16));
                    if (val <= thr) {
                        const int pos = j * 512 + lane * 8 + q * 2 + hi;
                        const int inb = pos & 63;
                        const unsigned slot = atomicAdd(&cntL[w], 1u);
                        if (slot < MAXC)
                            candL[w][slot] = (pos >> 6) * 64 + (inb & 3) * 16 + (inb >> 2);
                    }
                }
            }
        }
    }
    __syncthreads();

    const int cnt = (int)cntL[w];
    int id;
    if (cnt == 1) {
        id = candL[w][0] & (NE - 1);
    } else {
        const float zn = znorm[row];
        const float4* zp4 = (const float4*)(z + (size_t)row * DDIM);
        unsigned long long best = ~0ULL;
        if (cnt >= 2 && cnt <= MAXC) {
            if (lane < cnt)
                best = exact_key(zp4, emb, bnorm, zn, candL[w][lane] & (NE - 1));
        } else {             // cnt==0 (impossible) or overflow: exact scan of all codes
            for (int c = lane; c < NE; c += 64) {
                const unsigned long long k = exact_key(zp4, emb, bnorm, zn, c);
                if (k < best) best = k;
            }
        }
        #pragma unroll
        for (int m = 32; m; m >>= 1) {
            const unsigned long long ov = __shfl_xor(best, m);
            if (ov < best) best = ov;
        }
        id = (int)(__shfl(best, 0) & (unsigned long long)(NE - 1));
    }

    const float* zp = z + (size_t)row * DDIM;
    const float* ep = emb + (size_t)id * DDIM;
    float* op = out + 1 + (size_t)row * DDIM;
    float d2 = 0.f;
    #pragma unroll
    for (int m = 0; m < 8; ++m) {
        const int k = m * 64 + lane;
        const float e = ep[k];
        const float zv = zp[k];
        const float t = e - zv;          // two-step rounding matches reference STE
        op[k] = zv + t;
        d2 = fmaf(t, t, d2);
    }
    #pragma unroll
    for (int m = 32; m; m >>= 1) d2 += __shfl_xor(d2, m);
    if (lane == 0) {
        atomicAdd(&counts[id], 1u);
        d2buf[row] = d2;
        out[1 + (size_t)NZ + row] = (float)id;
    }
}

// ---------------- kernel 4: finalize loss + perplexity ----------------
__global__ void k_final(const float* __restrict__ d2buf, const unsigned* __restrict__ counts,
                        float* __restrict__ out) {
    __shared__ double sh[256];
    __shared__ float  shf[256];
    const int tid = threadIdx.x;
    double ent = 0.0;
    for (int i = tid; i < NE; i += 256) {
        const double p = (double)counts[i] / (double)NROWS;
        ent += p * log(p + 1e-10);
    }
    float sse = 0.f;
    for (int i = tid; i < NROWS; i += 256) sse += d2buf[i];
    sh[tid] = ent; shf[tid] = sse;
    __syncthreads();
    for (int s = 128; s; s >>= 1) {
        if (tid < s) { sh[tid] += sh[tid + s]; shf[tid] += shf[tid + s]; }
        __syncthreads();
    }
    if (tid == 0) {
        out[0] = 1.25f * (shf[0] / (float)NZ);
        out[1 + (size_t)NZ + NROWS] = (float)exp(-sh[0]);
    }
}

extern "C" void kernel_launch(void* const* d_in, const int* in_sizes, int n_in,
                              void* d_out, int out_size, void* d_ws, size_t ws_size,
                              hipStream_t stream) {
    const float* z   = (const float*)d_in[0];
    const float* emb = (const float*)d_in[1];
    float* out = (float*)d_out;
    char* ws = (char*)d_ws;

    // zh/eh live inside out[1..NZ]: written by k_prep, read by k_mfma, and only
    // k_pg (strictly later in stream order) writes out -> no overlap anywhere.
    ushort* zh = (ushort*)(out + 4);                       // 16 MB
    ushort* eh = (ushort*)(out + 4 + 4194304);             //  4 MB

    size_t off = 0;
    float*    bnorm  = (float*)(ws + off); off += (size_t)NE * 4;          // 16KB
    unsigned* counts = (unsigned*)(ws + off); off += (size_t)NE * 4;       // 16KB
    float*    d2buf  = (float*)(ws + off); off += (size_t)NROWS * 4;       // 64KB
    float*    znorm  = (float*)(ws + off); off += (size_t)NROWS * 4;       // 64KB
    ushort*   sbuf   = (ushort*)(ws + off); off += (size_t)NROWS * NE * 2; // 128MB (R9-verified fit)
    float*    rowblkmin = (float*)(ws + off); off += (size_t)NROWS * 64 * 4; // 4MB
    const bool guided = ws_size >= off;

    k_prep<<<1280, 256, 0, stream>>>(z, emb, zh, eh, znorm, bnorm, counts);
    if (guided) {
        k_mfma<1><<<dim3(NROWS / 128, NE / 128), 256, 0, stream>>>(zh, eh, bnorm, sbuf, rowblkmin);
        k_pg<1><<<NROWS / 4, 256, 0, stream>>>(sbuf, rowblkmin, z, emb, znorm, bnorm, out, counts, d2buf);
    } else {
        k_mfma<0><<<dim3(NROWS / 128, NE / 128), 256, 0, stream>>>(zh, eh, bnorm, sbuf, rowblkmin);
        k_pg<0><<<NROWS / 4, 256, 0, stream>>>(sbuf, rowblkmin, z, emb, znorm, bnorm, out, counts, d2buf);
    }
    k_final<<<1, 256, 0, stream>>>(d2buf, counts, out);
}